// Round 9
// baseline (289.749 us; speedup 1.0000x reference)
//
#include <hip/hip_runtime.h>
#include <hip/hip_bf16.h>
#include <stdint.h>

// Problem: B=8192, E=1024, P=512. x:[8192,2048] f32, w:[1024,512] f32, b:[512] f32.
// out: scalar = mean_i( -S[i,i^4096]/T + log(sum_{j!=i} exp(S[i,j]/T)) ),
// S = zn zn^T (symmetric -> upper triangle of 128x128 blocks), T=0.1.
// Pipeline: prep (wt=bf16(w^T), sumexp=0, out=0) -> projnorm (fused relu-GEMM +
// row-norm + fp8 quant; register-double-buffered, barrier-free K-loop) ->
// gemm2 (fp8 MX 16x16x128, R6-proven) -> finalize (16-block atomic mean).
// Flat-row identity: z[8192][1024] row r = [proj(x_flat[2r]) || proj(x_flat[2r+1])],
// so zn8 byte addr = f*512 + n for flat row f, col n.
//
// ws layout (bytes):
//   wt  bf16 [512][1024]    @ 0
//   zn8 fp8  [8192][1024]   @ 68157440
//   sumexp f32[8192]        @ 84934656
//   pos    f32[8192]        @ 84967424

typedef __attribute__((ext_vector_type(8))) __bf16 bf16x8;
typedef __attribute__((ext_vector_type(4))) float f32x4;
typedef __attribute__((ext_vector_type(4))) int i32x4;
typedef __attribute__((ext_vector_type(8))) int i32x8;

__device__ __forceinline__ unsigned short f2bf(float f) {
  union { float f; unsigned int u; } v; v.f = f;
  unsigned int u = v.u;
  u += 0x7FFFu + ((u >> 16) & 1u);
  return (unsigned short)(u >> 16);
}

// pack two relu'd f32 (trunc to bf16): low short = a, high short = b.
// (uniform truncation bias cancels under row-normalization)
__device__ __forceinline__ unsigned int rpack(float a, float b) {
  return __builtin_amdgcn_perm(__float_as_uint(fmaxf(b, 0.f)),
                               __float_as_uint(fmaxf(a, 0.f)), 0x07060302u);
}

__device__ __forceinline__ bf16x8 pack8(float4 lo, float4 hi) {
  union { unsigned int i[4]; bf16x8 v; } u;
  u.i[0] = rpack(lo.x, lo.y);
  u.i[1] = rpack(lo.z, lo.w);
  u.i[2] = rpack(hi.x, hi.y);
  u.i[3] = rpack(hi.z, hi.w);
  return u.v;
}

// ---------------- prep: wt = bf16(w^T); sumexp = 0; out = 0 ------------------
__global__ __launch_bounds__(256) void prep_kernel(
    const float* __restrict__ w, unsigned short* __restrict__ wt,
    float* __restrict__ sumexp, float* __restrict__ out) {
  int tid = blockIdx.x * 256 + threadIdx.x;      // 2048 blocks -> 524288
  int k = tid & 1023, n = tid >> 10;
  wt[(n << 10) + k] = f2bf(w[k * 512 + n]);
  if (tid < 8192) sumexp[tid] = 0.f;
  if (tid == 0) out[0] = 0.f;
}

// -------- projnorm: fused relu(x)@w+b, row-norm, fp8 quant -------------------
// Block: 16 flat rows x 512 N. 4 waves, wave w: n-range [w*128,+128). Grid 1024.
// A-frags built in regs from x (relu + bf16-trunc pack); B-frags read directly
// from L2-resident wt. Register double-buffer: iter it+1's loads issued before
// iter it's MFMAs -> vmcnt wait covered by a full MFMA phase + 4 blocks/CU.
// MFMA A: m = L&15, k = (L>>4)*8+j. C/D: col(n) = L&15, row(m) = (L>>4)*4+reg.
__global__ __launch_bounds__(256) void projnorm_kernel(
    const float* __restrict__ x, const unsigned short* __restrict__ wt,
    const float* __restrict__ bias, unsigned char* __restrict__ zn8) {
  int tid = threadIdx.x, L = tid & 63, w = tid >> 6;
  int l4 = L & 15, q = L >> 4;
  int i0 = blockIdx.x * 16;

  f32x4 acc[8];
#pragma unroll
  for (int nt = 0; nt < 8; ++nt) acc[nt] = (f32x4)0.f;

  const float* A0 = x + (size_t)(i0 + l4) * 1024 + q * 8;
  const unsigned short* B0 = wt + (size_t)(w * 128 + l4) * 1024 + q * 8;

  float4 ab[2][2];
  bf16x8 bb[2][8];
  ab[0][0] = *(const float4*)A0;
  ab[0][1] = *(const float4*)(A0 + 4);
#pragma unroll
  for (int nt = 0; nt < 8; ++nt)
    bb[0][nt] = *(const bf16x8*)(B0 + nt * 16384);

#pragma unroll 2
  for (int it = 0; it < 32; ++it) {
    int cur = it & 1, nxt = cur ^ 1;
    if (it < 31) {
      int kn = (it + 1) * 32;
      ab[nxt][0] = *(const float4*)(A0 + kn);
      ab[nxt][1] = *(const float4*)(A0 + kn + 4);
#pragma unroll
      for (int nt = 0; nt < 8; ++nt)
        bb[nxt][nt] = *(const bf16x8*)(B0 + nt * 16384 + kn);
    }
    bf16x8 af = pack8(ab[cur][0], ab[cur][1]);
#pragma unroll
    for (int nt = 0; nt < 8; ++nt)
      acc[nt] = __builtin_amdgcn_mfma_f32_16x16x32_bf16(af, bb[cur][nt], acc[nt], 0, 0, 0);
  }

  // epilogue: +bias, ssq over z-row (= flat-row pair), inv = 16/max(||z||,eps),
  // fp8 quantize, write zn8[f*512+n].
  __shared__ float prt[4][16];
  __shared__ float sinv[16];
  float bn[8];
#pragma unroll
  for (int nt = 0; nt < 8; ++nt) bn[nt] = bias[w * 128 + nt * 16 + l4];
  float sp[4];
#pragma unroll
  for (int r = 0; r < 4; ++r) {
    float s = 0.f;
#pragma unroll
    for (int nt = 0; nt < 8; ++nt) {
      float v = acc[nt][r] + bn[nt];
      acc[nt][r] = v;
      s += v * v;
    }
    sp[r] = s;
  }
#pragma unroll
  for (int r = 0; r < 4; ++r) {
    float v2 = sp[r];
    v2 += __shfl_xor(v2, 1); v2 += __shfl_xor(v2, 2);
    v2 += __shfl_xor(v2, 4); v2 += __shfl_xor(v2, 8);
    sp[r] = v2;
  }
  if (l4 == 0) {
#pragma unroll
    for (int r = 0; r < 4; ++r) prt[w][q * 4 + r] = sp[r];
  }
  __syncthreads();
  if (tid < 8) {
    float ssq = 0.f;
#pragma unroll
    for (int w2 = 0; w2 < 4; ++w2)
      ssq += prt[w2][2 * tid] + prt[w2][2 * tid + 1];
    float inv = 16.f / fmaxf(sqrtf(ssq), 1e-8f);
    sinv[2 * tid] = inv;
    sinv[2 * tid + 1] = inv;
  }
  __syncthreads();
#pragma unroll
  for (int r = 0; r < 4; ++r) {
    int fl = q * 4 + r;
    float sc = sinv[fl];
    size_t base = (size_t)(i0 + fl) * 512 + w * 128 + l4;
#pragma unroll
    for (int nt = 0; nt < 8; ++nt) {
      float v = acc[nt][r] * sc;
      int p = __builtin_amdgcn_cvt_pk_fp8_f32(v, v, 0, false);
      zn8[base + nt * 16] = (unsigned char)(p & 0xFF);
    }
  }
}

// -------- GEMM2 fp8 symmetric: 16x16x128 MX, 4x4 grid, BK=128 (R6-proven) ----
// LDS tile (16 KB), 4 panels of 256x16B units, XOR-swizzled positions
// p = u ^ ((u>>3)&7) (u = row*2 + h); staging realizes it via lane-side
// source permutation lp = L ^ ((L>>3)&7).
// A-frag lane L: m = L&15, k = (L>>4)*32 + j. C/D: col=L&15, row=(L>>4)*4+reg.
__global__ __launch_bounds__(256, 3) void gemm2_kernel(
    const unsigned char* __restrict__ zn8,
    float* __restrict__ sumexp, float* __restrict__ pos) {
  __shared__ unsigned char As[16384] __attribute__((aligned(16)));
  __shared__ unsigned char Bs[16384] __attribute__((aligned(16)));
  int rem = blockIdx.x, bi = 0;
  while (rem >= 64 - bi) { rem -= 64 - bi; ++bi; }
  int bj = bi + rem;
  bool diag = (bi == bj);
  int i0 = bi * 128, j0 = bj * 128;

  int tid = threadIdx.x, L = tid & 63, w = tid >> 6;
  int wm = w >> 1, wn = w & 1;
  int l4 = L & 15;
  int panel = (L >> 4) * 4096;

  // swizzled staging source: position P = w*64 + L  ->  u = w*64 + lp
  int lp = L ^ ((L >> 3) & 7);
  int srow = w * 32 + (lp >> 1), sh = lp & 1;

  f32x4 acc[4][4];
#pragma unroll
  for (int a = 0; a < 4; ++a)
#pragma unroll
    for (int bq = 0; bq < 4; ++bq) acc[a][bq] = (f32x4)0.f;

  const unsigned char* Ag = zn8 + (i0 + srow) * 1024 + sh * 16;
  const unsigned char* Bg = zn8 + (j0 + srow) * 1024 + sh * 16;
  const unsigned char* Bsrc = diag ? (const unsigned char*)As : (const unsigned char*)Bs;

#pragma unroll 1
  for (int k0 = 0; k0 < 1024; k0 += 128) {
    __syncthreads();
#pragma unroll
    for (int t = 0; t < 4; ++t)
      __builtin_amdgcn_global_load_lds(
          (const __attribute__((address_space(1))) void*)(Ag + k0 + t * 32),
          (__attribute__((address_space(3))) void*)(As + t * 4096 + (tid & ~63) * 16),
          16, 0, 0);
    if (!diag) {
#pragma unroll
      for (int t = 0; t < 4; ++t)
        __builtin_amdgcn_global_load_lds(
            (const __attribute__((address_space(1))) void*)(Bg + k0 + t * 32),
            (__attribute__((address_space(3))) void*)(Bs + t * 4096 + (tid & ~63) * 16),
            16, 0, 0);
    }
    __syncthreads();
    // preload A fragments (swizzled positions)
    i32x8 afr[4];
#pragma unroll
    for (int mt = 0; mt < 4; ++mt) {
      int row = wm * 64 + mt * 16 + l4;
      int p0 = (row * 2) ^ ((row >> 2) & 7);
      i32x4 lo = *(const i32x4*)(As + panel + p0 * 16);
      i32x4 hi = *(const i32x4*)(As + panel + (p0 ^ 1) * 16);
      afr[mt] = (i32x8){lo.x, lo.y, lo.z, lo.w, hi.x, hi.y, hi.z, hi.w};
    }
#pragma unroll
    for (int nt = 0; nt < 4; ++nt) {
      int row = wn * 64 + nt * 16 + l4;
      int p0 = (row * 2) ^ ((row >> 2) & 7);
      i32x4 lo = *(const i32x4*)(Bsrc + panel + p0 * 16);
      i32x4 hi = *(const i32x4*)(Bsrc + panel + (p0 ^ 1) * 16);
      i32x8 bfr = (i32x8){lo.x, lo.y, lo.z, lo.w, hi.x, hi.y, hi.z, hi.w};
#pragma unroll
      for (int mt = 0; mt < 4; ++mt)
        acc[mt][nt] = __builtin_amdgcn_mfma_scale_f32_16x16x128_f8f6f4(
            afr[mt], bfr, acc[mt][nt], 0, 0,
            0, 0x7F7F7F7F, 0, 0x7F7F7F7F);
    }
  }

  // epilogue (verified): s = acc*10/256; diag mask; pos; exp;
  // row-sums (lane bits 0-3) + col-sums (lane bits 4-5) -> atomics.
  const float SC = 10.0f / 256.0f;
  float rs[4][4];
  float cs[4] = {0.f, 0.f, 0.f, 0.f};
#pragma unroll
  for (int mt = 0; mt < 4; ++mt)
#pragma unroll
    for (int r = 0; r < 4; ++r) rs[mt][r] = 0.f;
  int ib = i0 + wm * 64 + ((L >> 4) << 2);
  int jb = j0 + wn * 64 + l4;
#pragma unroll
  for (int mt = 0; mt < 4; ++mt)
#pragma unroll
    for (int nt = 0; nt < 4; ++nt) {
      int j = jb + nt * 16;
#pragma unroll
      for (int r = 0; r < 4; ++r) {
        int i = ib + mt * 16 + r;
        float s = acc[mt][nt][r] * SC;
        if (j == (i ^ 4096)) { pos[i] = s; pos[j] = s; }
        float e = (i == j) ? 0.f : __expf(s);
        rs[mt][r] += e;
        if (!diag) cs[nt] += e;
      }
    }
#pragma unroll
  for (int mt = 0; mt < 4; ++mt)
#pragma unroll
    for (int r = 0; r < 4; ++r) {
      float v = rs[mt][r];
      v += __shfl_xor(v, 1); v += __shfl_xor(v, 2);
      v += __shfl_xor(v, 4); v += __shfl_xor(v, 8);
      rs[mt][r] = v;
    }
  int sel = l4;
  float myv = rs[0][0];
#pragma unroll
  for (int mt = 0; mt < 4; ++mt)
#pragma unroll
    for (int r = 0; r < 4; ++r)
      if (sel == mt * 4 + r) myv = rs[mt][r];
  int rowi = i0 + wm * 64 + (sel >> 2) * 16 + ((L >> 4) << 2) + (sel & 3);
  atomicAdd(&sumexp[rowi], myv);
  if (!diag) {
#pragma unroll
    for (int nt = 0; nt < 4; ++nt) {
      float v = cs[nt];
      v += __shfl_xor(v, 16); v += __shfl_xor(v, 32);
      if ((L >> 4) == 0) atomicAdd(&sumexp[jb + nt * 16], v);
    }
  }
}

// -------- finalize: out += mean-partial(log(sumexp) - pos), 16 blocks --------
__global__ __launch_bounds__(512) void finalize_kernel(
    const float* __restrict__ sumexp, const float* __restrict__ pos,
    float* __restrict__ out) {
  int t = threadIdx.x;
  int i = blockIdx.x * 512 + t;
  float s = logf(sumexp[i]) - pos[i];
#pragma unroll
  for (int off = 1; off < 64; off <<= 1) s += __shfl_xor(s, off);
  __shared__ float red[8];
  if ((t & 63) == 0) red[t >> 6] = s;
  __syncthreads();
  if (t == 0) {
    float tot = 0.f;
    for (int k2 = 0; k2 < 8; ++k2) tot += red[k2];
    atomicAdd(out, tot * (1.0f / 8192.0f));
  }
}

extern "C" void kernel_launch(void* const* d_in, const int* in_sizes, int n_in,
                              void* d_out, int out_size, void* d_ws, size_t ws_size,
                              hipStream_t stream) {
  const float* x = (const float*)d_in[0];
  const float* w = (const float*)d_in[1];
  const float* b = (const float*)d_in[2];
  float* out = (float*)d_out;
  char* ws = (char*)d_ws;
  unsigned short* wt = (unsigned short*)(ws);
  unsigned char* zn8 = (unsigned char*)(ws + 68157440);
  float* sumexp      = (float*)(ws + 84934656);
  float* pos         = (float*)(ws + 84967424);

  prep_kernel<<<2048, 256, 0, stream>>>(w, wt, sumexp, out);
  projnorm_kernel<<<1024, 256, 0, stream>>>(x, wt, b, zn8);
  gemm2_kernel<<<2080, 256, 0, stream>>>(zn8, sumexp, pos);
  finalize_kernel<<<16, 512, 0, stream>>>(sumexp, pos, out);
}

// Round 10
// 198.059 us; speedup vs baseline: 1.4629x; 1.4629x over previous
//
#include <hip/hip_runtime.h>
#include <hip/hip_bf16.h>
#include <stdint.h>

// Problem: B=8192, E=1024, P=512. x:[8192,2048] f32, w:[1024,512] f32, b:[512] f32.
// out: scalar = mean_i( -S[i,i^4096]/T + log(sum_{j!=i} exp(S[i,j]/T)) ),
// S = zn zn^T (symmetric -> upper triangle of 128x128 blocks), T=0.1.
// Pipeline: prep (wt=bf16(w^T), zeros) -> gemm1f (LDS-staged relu-GEMM, f32-A
// cast on read, 64x128 tiles, 4 blocks/CU) -> norm (rownorm -> fp8*16) ->
// gemm2 (fp8 MX 16x16x128, R6-proven, 63.5us) -> finalize (16-block mean).
//
// ws layout (bytes):
//   wt  bf16 [512][1024]    @ 0
//   z   f32  [16384][512]   @ 34603008
//   zn8 fp8  [8192][1024]   @ 68157440
//   sumexp f32[8192]        @ 84934656
//   pos    f32[8192]        @ 84967424

typedef __attribute__((ext_vector_type(8))) __bf16 bf16x8;
typedef __attribute__((ext_vector_type(4))) float f32x4;
typedef __attribute__((ext_vector_type(4))) int i32x4;
typedef __attribute__((ext_vector_type(8))) int i32x8;

__device__ __forceinline__ unsigned short f2bf(float f) {
  union { float f; unsigned int u; } v; v.f = f;
  unsigned int u = v.u;
  u += 0x7FFFu + ((u >> 16) & 1u);
  return (unsigned short)(u >> 16);
}

// pack two relu'd f32 (trunc to bf16). Uniform truncation bias cancels under
// row-normalization.
__device__ __forceinline__ unsigned int rpack(float a, float b) {
  return __builtin_amdgcn_perm(__float_as_uint(fmaxf(b, 0.f)),
                               __float_as_uint(fmaxf(a, 0.f)), 0x07060302u);
}

__device__ __forceinline__ bf16x8 pack8(float4 lo, float4 hi) {
  union { unsigned int i[4]; bf16x8 v; } u;
  u.i[0] = rpack(lo.x, lo.y);
  u.i[1] = rpack(lo.z, lo.w);
  u.i[2] = rpack(hi.x, hi.y);
  u.i[3] = rpack(hi.z, hi.w);
  return u.v;
}

// ---------------- prep: wt = bf16(w^T); sumexp = 0; out = 0 ------------------
__global__ __launch_bounds__(256) void prep_kernel(
    const float* __restrict__ w, unsigned short* __restrict__ wt,
    float* __restrict__ sumexp, float* __restrict__ out) {
  int tid = blockIdx.x * 256 + threadIdx.x;      // 2048 blocks -> 524288
  int k = tid & 1023, n = tid >> 10;
  wt[(n << 10) + k] = f2bf(w[k * 512 + n]);
  if (tid < 8192) sumexp[tid] = 0.f;
  if (tid == 0) out[0] = 0.f;
}

// -------- gemm1f: z[16384,512] = relu(x) @ wt^T + b --------------------------
// Block 64 M x 128 N, 4 waves (wm = w>>1 over M32, wn = w&1 over N64), BK=32.
// A staged as raw f32 (8 KB = 512 units of 16B/4f32), unit u=(row=u>>3,
// slot=u&7), stored at p = u ^ ((u>>3)&7); relu+bf16 pack on LDS read.
// B staged bf16 (8 KB = 512 units of 16B/8bf16), u=(n=u>>2, slot=u&3),
// stored at p = u ^ ((u>>2)&7). Both swizzles conflict-free for frag b128s.
// A-frag: m=L&15, k=(L>>4)*8+j. C/D: col=L&15, row=(L>>4)*4+reg.
__global__ __launch_bounds__(256) void gemm1f_kernel(
    const float* __restrict__ x, const unsigned short* __restrict__ wt,
    const float* __restrict__ bias, float* __restrict__ z) {
  __shared__ float As[2048] __attribute__((aligned(16)));          // 8 KB
  __shared__ unsigned short Bs[4096] __attribute__((aligned(16))); // 8 KB
  int tid = threadIdx.x, L = tid & 63, w = tid >> 6;
  int wm = w >> 1, wn = w & 1;
  int l4 = L & 15, q = L >> 4;
  int i0 = blockIdx.x * 64, n0 = blockIdx.y * 128;

  f32x4 acc[2][4];
#pragma unroll
  for (int mt = 0; mt < 2; ++mt)
#pragma unroll
    for (int nt = 0; nt < 4; ++nt) acc[mt][nt] = (f32x4)0.f;

  // staging source units (lane-side XOR realizes the swizzles)
  int uA = (tid & 255) ^ ((L >> 3) & 7);     // P = t*256 + tid
  int rowA = uA >> 3, slotA = uA & 7;
  int uB = (tid & 255) ^ ((L >> 2) & 7);
  int rowB = uB >> 2, slotB = uB & 3;
  const float* Asrc = x + (size_t)(i0 + rowA) * 1024 + slotA * 4;
  const unsigned short* Bsrc = wt + (size_t)(n0 + rowB) * 1024 + slotB * 8;

  for (int k0 = 0; k0 < 1024; k0 += 32) {
    __syncthreads();
#pragma unroll
    for (int t = 0; t < 2; ++t) {
      int base = t * 256 + (tid & ~63);
      __builtin_amdgcn_global_load_lds(
          (const __attribute__((address_space(1))) void*)(Asrc + (t * 32) * 1024 + k0),
          (__attribute__((address_space(3))) void*)(As + base * 4),
          16, 0, 0);
    }
#pragma unroll
    for (int t = 0; t < 2; ++t) {
      int base = t * 256 + (tid & ~63);
      __builtin_amdgcn_global_load_lds(
          (const __attribute__((address_space(1))) void*)(Bsrc + (t * 64) * 1024 + k0),
          (__attribute__((address_space(3))) void*)(Bs + base * 8),
          16, 0, 0);
    }
    __syncthreads();
    // A frags: relu + pack from f32 LDS
    bf16x8 af[2];
#pragma unroll
    for (int mt = 0; mt < 2; ++mt) {
      int r = wm * 32 + mt * 16 + l4;
      int u0 = r * 8 + q * 2;
      int p0 = u0 ^ (r & 7);
      float4 lo = *(const float4*)(As + p0 * 4);
      float4 hi = *(const float4*)(As + (p0 ^ 1) * 4);
      af[mt] = pack8(lo, hi);
    }
#pragma unroll
    for (int nt = 0; nt < 4; ++nt) {
      int n = wn * 64 + nt * 16 + l4;
      int u = n * 4 + q;
      int p = u ^ (n & 7);
      bf16x8 bf = *(const bf16x8*)(Bs + p * 8);
#pragma unroll
      for (int mt = 0; mt < 2; ++mt)
        acc[mt][nt] = __builtin_amdgcn_mfma_f32_16x16x32_bf16(
            af[mt], bf, acc[mt][nt], 0, 0, 0);
    }
  }
  // epilogue: + bias, write z f32
#pragma unroll
  for (int nt = 0; nt < 4; ++nt) {
    int n = n0 + wn * 64 + nt * 16 + l4;
    float bn = bias[n];
#pragma unroll
    for (int mt = 0; mt < 2; ++mt)
#pragma unroll
      for (int r = 0; r < 4; ++r) {
        int i = i0 + wm * 32 + mt * 16 + q * 4 + r;
        z[(size_t)i * 512 + n] = acc[mt][nt][r] + bn;
      }
  }
}

// -------- norm: zn8 = fp8_e4m3( 16 * z_row / max(||z_row||,eps) ) ------------
__global__ __launch_bounds__(256) void norm_kernel(const float* __restrict__ z,
                                                   unsigned char* __restrict__ zn8) {
  int row = blockIdx.x, t = threadIdx.x;
  float4 v = ((const float4*)z)[row * 256 + t];
  float ss = v.x * v.x + v.y * v.y + v.z * v.z + v.w * v.w;
#pragma unroll
  for (int off = 1; off < 64; off <<= 1) ss += __shfl_xor(ss, off);
  __shared__ float red[4];
  if ((t & 63) == 0) red[t >> 6] = ss;
  __syncthreads();
  float tot = red[0] + red[1] + red[2] + red[3];
  float inv = 16.f / fmaxf(sqrtf(tot), 1e-8f);
  int p = __builtin_amdgcn_cvt_pk_fp8_f32(v.x * inv, v.y * inv, 0, false);
  p = __builtin_amdgcn_cvt_pk_fp8_f32(v.z * inv, v.w * inv, p, true);
  ((int*)zn8)[row * 256 + t] = p;
}

// -------- GEMM2 fp8 symmetric: 16x16x128 MX, 4x4 grid, BK=128 (R6-proven) ----
// LDS tile (16 KB), 4 panels of 256x16B units, XOR-swizzled positions
// p = u ^ ((u>>3)&7) (u = row*2 + h); staging realizes it via lane-side
// source permutation lp = L ^ ((L>>3)&7).
// A-frag lane L: m = L&15, k = (L>>4)*32 + j. C/D: col=L&15, row=(L>>4)*4+reg.
__global__ __launch_bounds__(256, 3) void gemm2_kernel(
    const unsigned char* __restrict__ zn8,
    float* __restrict__ sumexp, float* __restrict__ pos) {
  __shared__ unsigned char As[16384] __attribute__((aligned(16)));
  __shared__ unsigned char Bs[16384] __attribute__((aligned(16)));
  int rem = blockIdx.x, bi = 0;
  while (rem >= 64 - bi) { rem -= 64 - bi; ++bi; }
  int bj = bi + rem;
  bool diag = (bi == bj);
  int i0 = bi * 128, j0 = bj * 128;

  int tid = threadIdx.x, L = tid & 63, w = tid >> 6;
  int wm = w >> 1, wn = w & 1;
  int l4 = L & 15;
  int panel = (L >> 4) * 4096;

  // swizzled staging source: position P = w*64 + L  ->  u = w*64 + lp
  int lp = L ^ ((L >> 3) & 7);
  int srow = w * 32 + (lp >> 1), sh = lp & 1;

  f32x4 acc[4][4];
#pragma unroll
  for (int a = 0; a < 4; ++a)
#pragma unroll
    for (int bq = 0; bq < 4; ++bq) acc[a][bq] = (f32x4)0.f;

  const unsigned char* Ag = zn8 + (i0 + srow) * 1024 + sh * 16;
  const unsigned char* Bg = zn8 + (j0 + srow) * 1024 + sh * 16;
  const unsigned char* Bsrc = diag ? (const unsigned char*)As : (const unsigned char*)Bs;

#pragma unroll 1
  for (int k0 = 0; k0 < 1024; k0 += 128) {
    __syncthreads();
#pragma unroll
    for (int t = 0; t < 4; ++t)
      __builtin_amdgcn_global_load_lds(
          (const __attribute__((address_space(1))) void*)(Ag + k0 + t * 32),
          (__attribute__((address_space(3))) void*)(As + t * 4096 + (tid & ~63) * 16),
          16, 0, 0);
    if (!diag) {
#pragma unroll
      for (int t = 0; t < 4; ++t)
        __builtin_amdgcn_global_load_lds(
            (const __attribute__((address_space(1))) void*)(Bg + k0 + t * 32),
            (__attribute__((address_space(3))) void*)(Bs + t * 4096 + (tid & ~63) * 16),
            16, 0, 0);
    }
    __syncthreads();
    // preload A fragments (swizzled positions)
    i32x8 afr[4];
#pragma unroll
    for (int mt = 0; mt < 4; ++mt) {
      int row = wm * 64 + mt * 16 + l4;
      int p0 = (row * 2) ^ ((row >> 2) & 7);
      i32x4 lo = *(const i32x4*)(As + panel + p0 * 16);
      i32x4 hi = *(const i32x4*)(As + panel + (p0 ^ 1) * 16);
      afr[mt] = (i32x8){lo.x, lo.y, lo.z, lo.w, hi.x, hi.y, hi.z, hi.w};
    }
#pragma unroll
    for (int nt = 0; nt < 4; ++nt) {
      int row = wn * 64 + nt * 16 + l4;
      int p0 = (row * 2) ^ ((row >> 2) & 7);
      i32x4 lo = *(const i32x4*)(Bsrc + panel + p0 * 16);
      i32x4 hi = *(const i32x4*)(Bsrc + panel + (p0 ^ 1) * 16);
      i32x8 bfr = (i32x8){lo.x, lo.y, lo.z, lo.w, hi.x, hi.y, hi.z, hi.w};
#pragma unroll
      for (int mt = 0; mt < 4; ++mt)
        acc[mt][nt] = __builtin_amdgcn_mfma_scale_f32_16x16x128_f8f6f4(
            afr[mt], bfr, acc[mt][nt], 0, 0,
            0, 0x7F7F7F7F, 0, 0x7F7F7F7F);
    }
  }

  // epilogue (verified): s = acc*10/256; diag mask; pos; exp;
  // row-sums (lane bits 0-3) + col-sums (lane bits 4-5) -> atomics.
  const float SC = 10.0f / 256.0f;
  float rs[4][4];
  float cs[4] = {0.f, 0.f, 0.f, 0.f};
#pragma unroll
  for (int mt = 0; mt < 4; ++mt)
#pragma unroll
    for (int r = 0; r < 4; ++r) rs[mt][r] = 0.f;
  int ib = i0 + wm * 64 + ((L >> 4) << 2);
  int jb = j0 + wn * 64 + l4;
#pragma unroll
  for (int mt = 0; mt < 4; ++mt)
#pragma unroll
    for (int nt = 0; nt < 4; ++nt) {
      int j = jb + nt * 16;
#pragma unroll
      for (int r = 0; r < 4; ++r) {
        int i = ib + mt * 16 + r;
        float s = acc[mt][nt][r] * SC;
        if (j == (i ^ 4096)) { pos[i] = s; pos[j] = s; }
        float e = (i == j) ? 0.f : __expf(s);
        rs[mt][r] += e;
        if (!diag) cs[nt] += e;
      }
    }
#pragma unroll
  for (int mt = 0; mt < 4; ++mt)
#pragma unroll
    for (int r = 0; r < 4; ++r) {
      float v = rs[mt][r];
      v += __shfl_xor(v, 1); v += __shfl_xor(v, 2);
      v += __shfl_xor(v, 4); v += __shfl_xor(v, 8);
      rs[mt][r] = v;
    }
  int sel = l4;
  float myv = rs[0][0];
#pragma unroll
  for (int mt = 0; mt < 4; ++mt)
#pragma unroll
    for (int r = 0; r < 4; ++r)
      if (sel == mt * 4 + r) myv = rs[mt][r];
  int rowi = i0 + wm * 64 + (sel >> 2) * 16 + ((L >> 4) << 2) + (sel & 3);
  atomicAdd(&sumexp[rowi], myv);
  if (!diag) {
#pragma unroll
    for (int nt = 0; nt < 4; ++nt) {
      float v = cs[nt];
      v += __shfl_xor(v, 16); v += __shfl_xor(v, 32);
      if ((L >> 4) == 0) atomicAdd(&sumexp[jb + nt * 16], v);
    }
  }
}

// -------- finalize: out += mean-partial(log(sumexp) - pos), 16 blocks --------
__global__ __launch_bounds__(512) void finalize_kernel(
    const float* __restrict__ sumexp, const float* __restrict__ pos,
    float* __restrict__ out) {
  int t = threadIdx.x;
  int i = blockIdx.x * 512 + t;
  float s = logf(sumexp[i]) - pos[i];
#pragma unroll
  for (int off = 1; off < 64; off <<= 1) s += __shfl_xor(s, off);
  __shared__ float red[8];
  if ((t & 63) == 0) red[t >> 6] = s;
  __syncthreads();
  if (t == 0) {
    float tot = 0.f;
    for (int k2 = 0; k2 < 8; ++k2) tot += red[k2];
    atomicAdd(out, tot * (1.0f / 8192.0f));
  }
}

extern "C" void kernel_launch(void* const* d_in, const int* in_sizes, int n_in,
                              void* d_out, int out_size, void* d_ws, size_t ws_size,
                              hipStream_t stream) {
  const float* x = (const float*)d_in[0];
  const float* w = (const float*)d_in[1];
  const float* b = (const float*)d_in[2];
  float* out = (float*)d_out;
  char* ws = (char*)d_ws;
  unsigned short* wt = (unsigned short*)(ws);
  float* z           = (float*)(ws + 34603008);
  unsigned char* zn8 = (unsigned char*)(ws + 68157440);
  float* sumexp      = (float*)(ws + 84934656);
  float* pos         = (float*)(ws + 84967424);

  prep_kernel<<<2048, 256, 0, stream>>>(w, wt, sumexp, out);
  gemm1f_kernel<<<dim3(256, 4), 256, 0, stream>>>(x, wt, b, z);
  norm_kernel<<<8192, 256, 0, stream>>>(z, zn8);
  gemm2_kernel<<<2080, 256, 0, stream>>>(zn8, sumexp, pos);
  finalize_kernel<<<16, 512, 0, stream>>>(sumexp, pos, out);
}

// Round 11
// 180.192 us; speedup vs baseline: 1.6080x; 1.0992x over previous
//
#include <hip/hip_runtime.h>
#include <hip/hip_bf16.h>
#include <stdint.h>

// Problem: B=8192, E=1024, P=512. x:[8192,2048] f32, w:[1024,512] f32, b:[512] f32.
// out: scalar = mean_i( -S[i,i^4096]/T + log(sum_{j!=i} exp(S[i,j]/T)) ),
// S = zn zn^T (symmetric -> upper triangle of 128x128 blocks), T=0.1.
// Pipeline: prep2 (x8 = fp8(16*relu(x)), wt8 = fp8(64*w^T), zeros) ->
// gemm1q (fp8 MX 16x16x128, gemm2-proven K-loop, 512 blocks, z bf16 = acc/1024+b)
// -> norm (bf16 rownorm -> fp8*16) -> gemm2 (R6-proven, 62us) -> finalize.
//
// ws layout (bytes):
//   wt8 fp8  [512][1024]    @ 0          (0.5 MB)
//   x8  fp8  [16384][1024]  @ 1048576    (16 MB)
//   z   bf16 [16384][512]   @ 17825792   (16 MB)
//   zn8 fp8  [8192][1024]   @ 68157440
//   sumexp f32[8192]        @ 84934656
//   pos    f32[8192]        @ 84967424

typedef __attribute__((ext_vector_type(8))) __bf16 bf16x8;
typedef __attribute__((ext_vector_type(4))) float f32x4;
typedef __attribute__((ext_vector_type(4))) int i32x4;
typedef __attribute__((ext_vector_type(8))) int i32x8;

__device__ __forceinline__ unsigned short f2bf(float f) {
  union { float f; unsigned int u; } v; v.f = f;
  unsigned int u = v.u;
  u += 0x7FFFu + ((u >> 16) & 1u);
  return (unsigned short)(u >> 16);
}

__device__ __forceinline__ float bf2f(unsigned short s) {
  return __uint_as_float(((unsigned int)s) << 16);
}

// ---------------- prep2: x8 = fp8(16*relu(x)); wt8 = fp8(64*w^T); zeros ------
__global__ __launch_bounds__(256) void prep2_kernel(
    const float* __restrict__ x, const float* __restrict__ w,
    unsigned char* __restrict__ x8, unsigned char* __restrict__ wt8,
    float* __restrict__ sumexp, float* __restrict__ out) {
  int tid = blockIdx.x * 256 + threadIdx.x;      // 16384 blocks -> 4,194,304
  float4 v = ((const float4*)x)[tid];
  int p = __builtin_amdgcn_cvt_pk_fp8_f32(fmaxf(v.x, 0.f) * 16.f,
                                          fmaxf(v.y, 0.f) * 16.f, 0, false);
  p = __builtin_amdgcn_cvt_pk_fp8_f32(fmaxf(v.z, 0.f) * 16.f,
                                      fmaxf(v.w, 0.f) * 16.f, p, true);
  ((int*)x8)[tid] = p;
  if (tid < 512 * 1024) {                        // wt8: coalesced writes
    int k = tid & 1023, n = tid >> 10;
    int q = __builtin_amdgcn_cvt_pk_fp8_f32(w[k * 512 + n] * 64.f, 0.f, 0, false);
    wt8[(n << 10) + k] = (unsigned char)(q & 0xFF);
  }
  if (tid < 8192) sumexp[tid] = 0.f;
  if (tid == 0) out[0] = 0.f;
}

// -------- gemm1q: z[16384,512](bf16) = relu(x)@w + b via fp8 MX --------------
// Exact gemm2 K-loop structure (proven): 128x128 tile, BK=128, XOR-swizzled
// 16 KB LDS per matrix, 16x mfma_scale_16x16x128 per barrier-pair, 8 iters.
// A-frag lane L: m = L&15, k = (L>>4)*32 + j. C/D: col=L&15, row=(L>>4)*4+reg.
// Epilogue: z = acc/1024 + bias (fp8 scales 16*64 undone), bf16 store.
__global__ __launch_bounds__(256) void gemm1q_kernel(
    const unsigned char* __restrict__ x8, const unsigned char* __restrict__ wt8,
    const float* __restrict__ bias, unsigned short* __restrict__ z) {
  __shared__ unsigned char As[16384] __attribute__((aligned(16)));
  __shared__ unsigned char Bs[16384] __attribute__((aligned(16)));
  int i0 = blockIdx.x * 128, n0 = blockIdx.y * 128;

  int tid = threadIdx.x, L = tid & 63, w = tid >> 6;
  int wm = w >> 1, wn = w & 1;
  int l4 = L & 15, q = L >> 4;
  int panel = q * 4096;

  int lp = L ^ ((L >> 3) & 7);
  int srow = w * 32 + (lp >> 1), sh = lp & 1;

  f32x4 acc[4][4];
#pragma unroll
  for (int a = 0; a < 4; ++a)
#pragma unroll
    for (int bq = 0; bq < 4; ++bq) acc[a][bq] = (f32x4)0.f;

  const unsigned char* Ag = x8 + (size_t)(i0 + srow) * 1024 + sh * 16;
  const unsigned char* Bg = wt8 + (size_t)(n0 + srow) * 1024 + sh * 16;

#pragma unroll 1
  for (int k0 = 0; k0 < 1024; k0 += 128) {
    __syncthreads();
#pragma unroll
    for (int t = 0; t < 4; ++t)
      __builtin_amdgcn_global_load_lds(
          (const __attribute__((address_space(1))) void*)(Ag + k0 + t * 32),
          (__attribute__((address_space(3))) void*)(As + t * 4096 + (tid & ~63) * 16),
          16, 0, 0);
#pragma unroll
    for (int t = 0; t < 4; ++t)
      __builtin_amdgcn_global_load_lds(
          (const __attribute__((address_space(1))) void*)(Bg + k0 + t * 32),
          (__attribute__((address_space(3))) void*)(Bs + t * 4096 + (tid & ~63) * 16),
          16, 0, 0);
    __syncthreads();
    i32x8 afr[4];
#pragma unroll
    for (int mt = 0; mt < 4; ++mt) {
      int row = wm * 64 + mt * 16 + l4;
      int p0 = (row * 2) ^ ((row >> 2) & 7);
      i32x4 lo = *(const i32x4*)(As + panel + p0 * 16);
      i32x4 hi = *(const i32x4*)(As + panel + (p0 ^ 1) * 16);
      afr[mt] = (i32x8){lo.x, lo.y, lo.z, lo.w, hi.x, hi.y, hi.z, hi.w};
    }
#pragma unroll
    for (int nt = 0; nt < 4; ++nt) {
      int row = wn * 64 + nt * 16 + l4;
      int p0 = (row * 2) ^ ((row >> 2) & 7);
      i32x4 lo = *(const i32x4*)(Bs + panel + p0 * 16);
      i32x4 hi = *(const i32x4*)(Bs + panel + (p0 ^ 1) * 16);
      i32x8 bfr = (i32x8){lo.x, lo.y, lo.z, lo.w, hi.x, hi.y, hi.z, hi.w};
#pragma unroll
      for (int mt = 0; mt < 4; ++mt)
        acc[mt][nt] = __builtin_amdgcn_mfma_scale_f32_16x16x128_f8f6f4(
            afr[mt], bfr, acc[mt][nt], 0, 0,
            0, 0x7F7F7F7F, 0, 0x7F7F7F7F);
    }
  }

  // epilogue: z = acc/1024 + bias -> bf16
  const float SC = 1.0f / 1024.0f;
#pragma unroll
  for (int nt = 0; nt < 4; ++nt) {
    int n = n0 + wn * 64 + nt * 16 + l4;
    float bn = bias[n];
#pragma unroll
    for (int mt = 0; mt < 4; ++mt) {
      int ib = i0 + wm * 64 + mt * 16 + q * 4;
#pragma unroll
      for (int r = 0; r < 4; ++r)
        z[(size_t)(ib + r) * 512 + n] = f2bf(acc[mt][nt][r] * SC + bn);
    }
  }
}

// -------- norm: zn8 = fp8_e4m3( 16 * z_row / max(||z_row||,eps) ), z bf16 ----
__global__ __launch_bounds__(256) void norm_kernel(
    const unsigned short* __restrict__ z, unsigned char* __restrict__ zn8) {
  int row = blockIdx.x, t = threadIdx.x;
  ushort4 u = ((const ushort4*)z)[row * 256 + t];
  float a0 = bf2f(u.x), a1 = bf2f(u.y), a2 = bf2f(u.z), a3 = bf2f(u.w);
  float ss = a0 * a0 + a1 * a1 + a2 * a2 + a3 * a3;
#pragma unroll
  for (int off = 1; off < 64; off <<= 1) ss += __shfl_xor(ss, off);
  __shared__ float red[4];
  if ((t & 63) == 0) red[t >> 6] = ss;
  __syncthreads();
  float tot = red[0] + red[1] + red[2] + red[3];
  float inv = 16.f / fmaxf(sqrtf(tot), 1e-8f);
  int p = __builtin_amdgcn_cvt_pk_fp8_f32(a0 * inv, a1 * inv, 0, false);
  p = __builtin_amdgcn_cvt_pk_fp8_f32(a2 * inv, a3 * inv, p, true);
  ((int*)zn8)[row * 256 + t] = p;
}

// -------- GEMM2 fp8 symmetric: 16x16x128 MX, 4x4 grid, BK=128 (R6-proven) ----
// LDS tile (16 KB), 4 panels of 256x16B units, XOR-swizzled positions
// p = u ^ ((u>>3)&7) (u = row*2 + h); staging realizes it via lane-side
// source permutation lp = L ^ ((L>>3)&7).
// A-frag lane L: m = L&15, k = (L>>4)*32 + j. C/D: col=L&15, row=(L>>4)*4+reg.
__global__ __launch_bounds__(256, 3) void gemm2_kernel(
    const unsigned char* __restrict__ zn8,
    float* __restrict__ sumexp, float* __restrict__ pos) {
  __shared__ unsigned char As[16384] __attribute__((aligned(16)));
  __shared__ unsigned char Bs[16384] __attribute__((aligned(16)));
  int rem = blockIdx.x, bi = 0;
  while (rem >= 64 - bi) { rem -= 64 - bi; ++bi; }
  int bj = bi + rem;
  bool diag = (bi == bj);
  int i0 = bi * 128, j0 = bj * 128;

  int tid = threadIdx.x, L = tid & 63, w = tid >> 6;
  int wm = w >> 1, wn = w & 1;
  int l4 = L & 15;
  int panel = (L >> 4) * 4096;

  // swizzled staging source: position P = w*64 + L  ->  u = w*64 + lp
  int lp = L ^ ((L >> 3) & 7);
  int srow = w * 32 + (lp >> 1), sh = lp & 1;

  f32x4 acc[4][4];
#pragma unroll
  for (int a = 0; a < 4; ++a)
#pragma unroll
    for (int bq = 0; bq < 4; ++bq) acc[a][bq] = (f32x4)0.f;

  const unsigned char* Ag = zn8 + (i0 + srow) * 1024 + sh * 16;
  const unsigned char* Bg = zn8 + (j0 + srow) * 1024 + sh * 16;
  const unsigned char* Bsrc = diag ? (const unsigned char*)As : (const unsigned char*)Bs;

#pragma unroll 1
  for (int k0 = 0; k0 < 1024; k0 += 128) {
    __syncthreads();
#pragma unroll
    for (int t = 0; t < 4; ++t)
      __builtin_amdgcn_global_load_lds(
          (const __attribute__((address_space(1))) void*)(Ag + k0 + t * 32),
          (__attribute__((address_space(3))) void*)(As + t * 4096 + (tid & ~63) * 16),
          16, 0, 0);
    if (!diag) {
#pragma unroll
      for (int t = 0; t < 4; ++t)
        __builtin_amdgcn_global_load_lds(
            (const __attribute__((address_space(1))) void*)(Bg + k0 + t * 32),
            (__attribute__((address_space(3))) void*)(Bs + t * 4096 + (tid & ~63) * 16),
            16, 0, 0);
    }
    __syncthreads();
    // preload A fragments (swizzled positions)
    i32x8 afr[4];
#pragma unroll
    for (int mt = 0; mt < 4; ++mt) {
      int row = wm * 64 + mt * 16 + l4;
      int p0 = (row * 2) ^ ((row >> 2) & 7);
      i32x4 lo = *(const i32x4*)(As + panel + p0 * 16);
      i32x4 hi = *(const i32x4*)(As + panel + (p0 ^ 1) * 16);
      afr[mt] = (i32x8){lo.x, lo.y, lo.z, lo.w, hi.x, hi.y, hi.z, hi.w};
    }
#pragma unroll
    for (int nt = 0; nt < 4; ++nt) {
      int row = wn * 64 + nt * 16 + l4;
      int p0 = (row * 2) ^ ((row >> 2) & 7);
      i32x4 lo = *(const i32x4*)(Bsrc + panel + p0 * 16);
      i32x4 hi = *(const i32x4*)(Bsrc + panel + (p0 ^ 1) * 16);
      i32x8 bfr = (i32x8){lo.x, lo.y, lo.z, lo.w, hi.x, hi.y, hi.z, hi.w};
#pragma unroll
      for (int mt = 0; mt < 4; ++mt)
        acc[mt][nt] = __builtin_amdgcn_mfma_scale_f32_16x16x128_f8f6f4(
            afr[mt], bfr, acc[mt][nt], 0, 0,
            0, 0x7F7F7F7F, 0, 0x7F7F7F7F);
    }
  }

  // epilogue (verified): s = acc*10/256; diag mask; pos; exp;
  // row-sums (lane bits 0-3) + col-sums (lane bits 4-5) -> atomics.
  const float SC = 10.0f / 256.0f;
  float rs[4][4];
  float cs[4] = {0.f, 0.f, 0.f, 0.f};
#pragma unroll
  for (int mt = 0; mt < 4; ++mt)
#pragma unroll
    for (int r = 0; r < 4; ++r) rs[mt][r] = 0.f;
  int ib = i0 + wm * 64 + ((L >> 4) << 2);
  int jb = j0 + wn * 64 + l4;
#pragma unroll
  for (int mt = 0; mt < 4; ++mt)
#pragma unroll
    for (int nt = 0; nt < 4; ++nt) {
      int j = jb + nt * 16;
#pragma unroll
      for (int r = 0; r < 4; ++r) {
        int i = ib + mt * 16 + r;
        float s = acc[mt][nt][r] * SC;
        if (j == (i ^ 4096)) { pos[i] = s; pos[j] = s; }
        float e = (i == j) ? 0.f : __expf(s);
        rs[mt][r] += e;
        if (!diag) cs[nt] += e;
      }
    }
#pragma unroll
  for (int mt = 0; mt < 4; ++mt)
#pragma unroll
    for (int r = 0; r < 4; ++r) {
      float v = rs[mt][r];
      v += __shfl_xor(v, 1); v += __shfl_xor(v, 2);
      v += __shfl_xor(v, 4); v += __shfl_xor(v, 8);
      rs[mt][r] = v;
    }
  int sel = l4;
  float myv = rs[0][0];
#pragma unroll
  for (int mt = 0; mt < 4; ++mt)
#pragma unroll
    for (int r = 0; r < 4; ++r)
      if (sel == mt * 4 + r) myv = rs[mt][r];
  int rowi = i0 + wm * 64 + (sel >> 2) * 16 + ((L >> 4) << 2) + (sel & 3);
  atomicAdd(&sumexp[rowi], myv);
  if (!diag) {
#pragma unroll
    for (int nt = 0; nt < 4; ++nt) {
      float v = cs[nt];
      v += __shfl_xor(v, 16); v += __shfl_xor(v, 32);
      if ((L >> 4) == 0) atomicAdd(&sumexp[jb + nt * 16], v);
    }
  }
}

// -------- finalize: out += mean-partial(log(sumexp) - pos), 16 blocks --------
__global__ __launch_bounds__(512) void finalize_kernel(
    const float* __restrict__ sumexp, const float* __restrict__ pos,
    float* __restrict__ out) {
  int t = threadIdx.x;
  int i = blockIdx.x * 512 + t;
  float s = logf(sumexp[i]) - pos[i];
#pragma unroll
  for (int off = 1; off < 64; off <<= 1) s += __shfl_xor(s, off);
  __shared__ float red[8];
  if ((t & 63) == 0) red[t >> 6] = s;
  __syncthreads();
  if (t == 0) {
    float tot = 0.f;
    for (int k2 = 0; k2 < 8; ++k2) tot += red[k2];
    atomicAdd(out, tot * (1.0f / 8192.0f));
  }
}

extern "C" void kernel_launch(void* const* d_in, const int* in_sizes, int n_in,
                              void* d_out, int out_size, void* d_ws, size_t ws_size,
                              hipStream_t stream) {
  const float* x = (const float*)d_in[0];
  const float* w = (const float*)d_in[1];
  const float* b = (const float*)d_in[2];
  float* out = (float*)d_out;
  char* ws = (char*)d_ws;
  unsigned char* wt8 = (unsigned char*)(ws);
  unsigned char* x8  = (unsigned char*)(ws + 1048576);
  unsigned short* z  = (unsigned short*)(ws + 17825792);
  unsigned char* zn8 = (unsigned char*)(ws + 68157440);
  float* sumexp      = (float*)(ws + 84934656);
  float* pos         = (float*)(ws + 84967424);

  prep2_kernel<<<16384, 256, 0, stream>>>(x, w, x8, wt8, sumexp, out);
  gemm1q_kernel<<<dim3(128, 4), 256, 0, stream>>>(x8, wt8, b, z);
  norm_kernel<<<8192, 256, 0, stream>>>(z, zn8);
  gemm2_kernel<<<2080, 256, 0, stream>>>(zn8, sumexp, pos);
  finalize_kernel<<<16, 512, 0, stream>>>(sumexp, pos, out);
}

// Round 12
// 174.942 us; speedup vs baseline: 1.6563x; 1.0300x over previous
//
#include <hip/hip_runtime.h>
#include <hip/hip_bf16.h>
#include <stdint.h>

// Problem: B=8192, E=1024, P=512. x:[8192,2048] f32, w:[1024,512] f32, b:[512] f32.
// out: scalar = mean_i( -S[i,i^4096]/T + log(sum_{j!=i} exp(S[i,j]/T)) ),
// S = zn zn^T (symmetric -> upper triangle of 128x128 blocks), T=0.1.
// Pipeline: prep2 (x8 = fp8(16*relu(x)), wt8 = fp8(64*w^T), zeros) ->
// gemm1q (fp8 MX, XCD-swizzled) -> norm -> gemm2 (fp8 MX, supertile-XCD
// swizzled triangle) -> finalize.
//
// ws layout (bytes):
//   wt8 fp8  [512][1024]    @ 0
//   x8  fp8  [16384][1024]  @ 1048576
//   z   bf16 [16384][512]   @ 17825792
//   zn8 fp8  [8192][1024]   @ 68157440
//   sumexp f32[8192]        @ 84934656
//   pos    f32[8192]        @ 84967424

typedef __attribute__((ext_vector_type(8))) __bf16 bf16x8;
typedef __attribute__((ext_vector_type(4))) float f32x4;
typedef __attribute__((ext_vector_type(4))) int i32x4;
typedef __attribute__((ext_vector_type(8))) int i32x8;

__device__ __forceinline__ unsigned short f2bf(float f) {
  union { float f; unsigned int u; } v; v.f = f;
  unsigned int u = v.u;
  u += 0x7FFFu + ((u >> 16) & 1u);
  return (unsigned short)(u >> 16);
}

__device__ __forceinline__ float bf2f(unsigned short s) {
  return __uint_as_float(((unsigned int)s) << 16);
}

// ---------------- prep2: x8 = fp8(16*relu(x)); wt8 = fp8(64*w^T); zeros ------
__global__ __launch_bounds__(256) void prep2_kernel(
    const float* __restrict__ x, const float* __restrict__ w,
    unsigned char* __restrict__ x8, unsigned char* __restrict__ wt8,
    float* __restrict__ sumexp, float* __restrict__ out) {
  int tid = blockIdx.x * 256 + threadIdx.x;
  float4 v = ((const float4*)x)[tid];
  int p = __builtin_amdgcn_cvt_pk_fp8_f32(fmaxf(v.x, 0.f) * 16.f,
                                          fmaxf(v.y, 0.f) * 16.f, 0, false);
  p = __builtin_amdgcn_cvt_pk_fp8_f32(fmaxf(v.z, 0.f) * 16.f,
                                      fmaxf(v.w, 0.f) * 16.f, p, true);
  ((int*)x8)[tid] = p;
  if (tid < 512 * 1024) {
    int k = tid & 1023, n = tid >> 10;
    int q = __builtin_amdgcn_cvt_pk_fp8_f32(w[k * 512 + n] * 64.f, 0.f, 0, false);
    wt8[(n << 10) + k] = (unsigned char)(q & 0xFF);
  }
  if (tid < 8192) sumexp[tid] = 0.f;
  if (tid == 0) out[0] = 0.f;
}

// -------- gemm1q: z[16384,512](bf16) = relu(x)@w + b via fp8 MX --------------
// gemm2-proven K-loop: 128x128 tile, BK=128, XOR-swizzled 16 KB LDS/matrix.
// XCD-locality: grid 512 (1D); XCD x owns i-tiles [x*16,+16), n innermost ->
// per-XCD working set = 2 MB x8 band + 0.5 MB wt8 (L2-resident).
// A-frag lane L: m=L&15, k=(L>>4)*32+j. C/D: col=L&15, row=(L>>4)*4+reg.
__global__ __launch_bounds__(256) void gemm1q_kernel(
    const unsigned char* __restrict__ x8, const unsigned char* __restrict__ wt8,
    const float* __restrict__ bias, unsigned short* __restrict__ z) {
  __shared__ unsigned char As[16384] __attribute__((aligned(16)));
  __shared__ unsigned char Bs[16384] __attribute__((aligned(16)));
  int b = blockIdx.x;
  int kk = b >> 3;
  int i0 = ((b & 7) * 16 + (kk >> 2)) * 128;
  int n0 = (kk & 3) * 128;

  int tid = threadIdx.x, L = tid & 63, w = tid >> 6;
  int wm = w >> 1, wn = w & 1;
  int l4 = L & 15, q = L >> 4;
  int panel = q * 4096;

  int lp = L ^ ((L >> 3) & 7);
  int srow = w * 32 + (lp >> 1), sh = lp & 1;

  f32x4 acc[4][4];
#pragma unroll
  for (int a = 0; a < 4; ++a)
#pragma unroll
    for (int bq = 0; bq < 4; ++bq) acc[a][bq] = (f32x4)0.f;

  const unsigned char* Ag = x8 + (size_t)(i0 + srow) * 1024 + sh * 16;
  const unsigned char* Bg = wt8 + (size_t)(n0 + srow) * 1024 + sh * 16;

#pragma unroll 1
  for (int k0 = 0; k0 < 1024; k0 += 128) {
    __syncthreads();
#pragma unroll
    for (int t = 0; t < 4; ++t)
      __builtin_amdgcn_global_load_lds(
          (const __attribute__((address_space(1))) void*)(Ag + k0 + t * 32),
          (__attribute__((address_space(3))) void*)(As + t * 4096 + (tid & ~63) * 16),
          16, 0, 0);
#pragma unroll
    for (int t = 0; t < 4; ++t)
      __builtin_amdgcn_global_load_lds(
          (const __attribute__((address_space(1))) void*)(Bg + k0 + t * 32),
          (__attribute__((address_space(3))) void*)(Bs + t * 4096 + (tid & ~63) * 16),
          16, 0, 0);
    __syncthreads();
    i32x8 afr[4];
#pragma unroll
    for (int mt = 0; mt < 4; ++mt) {
      int row = wm * 64 + mt * 16 + l4;
      int p0 = (row * 2) ^ ((row >> 2) & 7);
      i32x4 lo = *(const i32x4*)(As + panel + p0 * 16);
      i32x4 hi = *(const i32x4*)(As + panel + (p0 ^ 1) * 16);
      afr[mt] = (i32x8){lo.x, lo.y, lo.z, lo.w, hi.x, hi.y, hi.z, hi.w};
    }
#pragma unroll
    for (int nt = 0; nt < 4; ++nt) {
      int row = wn * 64 + nt * 16 + l4;
      int p0 = (row * 2) ^ ((row >> 2) & 7);
      i32x4 lo = *(const i32x4*)(Bs + panel + p0 * 16);
      i32x4 hi = *(const i32x4*)(Bs + panel + (p0 ^ 1) * 16);
      i32x8 bfr = (i32x8){lo.x, lo.y, lo.z, lo.w, hi.x, hi.y, hi.z, hi.w};
#pragma unroll
      for (int mt = 0; mt < 4; ++mt)
        acc[mt][nt] = __builtin_amdgcn_mfma_scale_f32_16x16x128_f8f6f4(
            afr[mt], bfr, acc[mt][nt], 0, 0,
            0, 0x7F7F7F7F, 0, 0x7F7F7F7F);
    }
  }

  // epilogue: z = acc/1024 + bias -> bf16
  const float SC = 1.0f / 1024.0f;
#pragma unroll
  for (int nt = 0; nt < 4; ++nt) {
    int n = n0 + wn * 64 + nt * 16 + l4;
    float bn = bias[n];
#pragma unroll
    for (int mt = 0; mt < 4; ++mt) {
      int ib = i0 + wm * 64 + mt * 16 + q * 4;
#pragma unroll
      for (int r = 0; r < 4; ++r)
        z[(size_t)(ib + r) * 512 + n] = f2bf(acc[mt][nt][r] * SC + bn);
    }
  }
}

// -------- norm: zn8 = fp8_e4m3( 16 * z_row / max(||z_row||,eps) ), z bf16 ----
__global__ __launch_bounds__(256) void norm_kernel(
    const unsigned short* __restrict__ z, unsigned char* __restrict__ zn8) {
  int row = blockIdx.x, t = threadIdx.x;
  ushort4 u = ((const ushort4*)z)[row * 256 + t];
  float a0 = bf2f(u.x), a1 = bf2f(u.y), a2 = bf2f(u.z), a3 = bf2f(u.w);
  float ss = a0 * a0 + a1 * a1 + a2 * a2 + a3 * a3;
#pragma unroll
  for (int off = 1; off < 64; off <<= 1) ss += __shfl_xor(ss, off);
  __shared__ float red[4];
  if ((t & 63) == 0) red[t >> 6] = ss;
  __syncthreads();
  float tot = red[0] + red[1] + red[2] + red[3];
  float inv = 16.f / fmaxf(sqrtf(tot), 1e-8f);
  int p = __builtin_amdgcn_cvt_pk_fp8_f32(a0 * inv, a1 * inv, 0, false);
  p = __builtin_amdgcn_cvt_pk_fp8_f32(a2 * inv, a3 * inv, p, true);
  ((int*)zn8)[row * 256 + t] = p;
}

// -------- GEMM2 fp8 symmetric: 16x16x128 MX, BK=128 (R6 loop) ----------------
// Supertile-XCD swizzle: 64x64 block-triangle partitioned into 8x8 supertiles
// of 8x8 blocks (A+B working set ~2 MB <= 4 MB per-XCD L2). Permutation
// g = (b&7)*260 + (b>>3) gives each XCD a contiguous supertile-ordered range.
// A-frag lane L: m=L&15, k=(L>>4)*32+j. C/D: col=L&15, row=(L>>4)*4+reg.
__global__ __launch_bounds__(256, 3) void gemm2_kernel(
    const unsigned char* __restrict__ zn8,
    float* __restrict__ sumexp, float* __restrict__ pos) {
  __shared__ unsigned char As[16384] __attribute__((aligned(16)));
  __shared__ unsigned char Bs[16384] __attribute__((aligned(16)));
  // --- supertile decode (pure bijection over the 2080 triangle blocks) ---
  int g = (blockIdx.x & 7) * 260 + (blockIdx.x >> 3);
  int SI = 0, rem = g;
#pragma unroll 1
  for (SI = 0; SI < 8; ++SI) {
    int rowcnt = 36 + (7 - SI) * 64;
    if (rem < rowcnt) break;
    rem -= rowcnt;
  }
  int bi, bj;
  if (rem < 36) {                       // diagonal supertile (8x8 triangle)
    int ti = 0;
    while (rem >= 8 - ti) { rem -= 8 - ti; ++ti; }
    bi = SI * 8 + ti;
    bj = bi + rem;
  } else {                              // off-diagonal supertile
    rem -= 36;
    int SJ = SI + 1 + (rem >> 6);
    int l = rem & 63;
    bi = SI * 8 + (l >> 3);
    bj = SJ * 8 + (l & 7);
  }
  bool diag = (bi == bj);
  int i0 = bi * 128, j0 = bj * 128;

  int tid = threadIdx.x, L = tid & 63, w = tid >> 6;
  int wm = w >> 1, wn = w & 1;
  int l4 = L & 15;
  int panel = (L >> 4) * 4096;

  int lp = L ^ ((L >> 3) & 7);
  int srow = w * 32 + (lp >> 1), sh = lp & 1;

  f32x4 acc[4][4];
#pragma unroll
  for (int a = 0; a < 4; ++a)
#pragma unroll
    for (int bq = 0; bq < 4; ++bq) acc[a][bq] = (f32x4)0.f;

  const unsigned char* Ag = zn8 + (i0 + srow) * 1024 + sh * 16;
  const unsigned char* Bg = zn8 + (j0 + srow) * 1024 + sh * 16;
  const unsigned char* Bsrc = diag ? (const unsigned char*)As : (const unsigned char*)Bs;

#pragma unroll 1
  for (int k0 = 0; k0 < 1024; k0 += 128) {
    __syncthreads();
#pragma unroll
    for (int t = 0; t < 4; ++t)
      __builtin_amdgcn_global_load_lds(
          (const __attribute__((address_space(1))) void*)(Ag + k0 + t * 32),
          (__attribute__((address_space(3))) void*)(As + t * 4096 + (tid & ~63) * 16),
          16, 0, 0);
    if (!diag) {
#pragma unroll
      for (int t = 0; t < 4; ++t)
        __builtin_amdgcn_global_load_lds(
            (const __attribute__((address_space(1))) void*)(Bg + k0 + t * 32),
            (__attribute__((address_space(3))) void*)(Bs + t * 4096 + (tid & ~63) * 16),
            16, 0, 0);
    }
    __syncthreads();
    i32x8 afr[4];
#pragma unroll
    for (int mt = 0; mt < 4; ++mt) {
      int row = wm * 64 + mt * 16 + l4;
      int p0 = (row * 2) ^ ((row >> 2) & 7);
      i32x4 lo = *(const i32x4*)(As + panel + p0 * 16);
      i32x4 hi = *(const i32x4*)(As + panel + (p0 ^ 1) * 16);
      afr[mt] = (i32x8){lo.x, lo.y, lo.z, lo.w, hi.x, hi.y, hi.z, hi.w};
    }
#pragma unroll
    for (int nt = 0; nt < 4; ++nt) {
      int row = wn * 64 + nt * 16 + l4;
      int p0 = (row * 2) ^ ((row >> 2) & 7);
      i32x4 lo = *(const i32x4*)(Bsrc + panel + p0 * 16);
      i32x4 hi = *(const i32x4*)(Bsrc + panel + (p0 ^ 1) * 16);
      i32x8 bfr = (i32x8){lo.x, lo.y, lo.z, lo.w, hi.x, hi.y, hi.z, hi.w};
#pragma unroll
      for (int mt = 0; mt < 4; ++mt)
        acc[mt][nt] = __builtin_amdgcn_mfma_scale_f32_16x16x128_f8f6f4(
            afr[mt], bfr, acc[mt][nt], 0, 0,
            0, 0x7F7F7F7F, 0, 0x7F7F7F7F);
    }
  }

  // epilogue (verified): s = acc*10/256; diag mask; pos; exp;
  // row-sums (lane bits 0-3) + col-sums (lane bits 4-5) -> atomics.
  const float SC = 10.0f / 256.0f;
  float rs[4][4];
  float cs[4] = {0.f, 0.f, 0.f, 0.f};
#pragma unroll
  for (int mt = 0; mt < 4; ++mt)
#pragma unroll
    for (int r = 0; r < 4; ++r) rs[mt][r] = 0.f;
  int ib = i0 + wm * 64 + ((L >> 4) << 2);
  int jb = j0 + wn * 64 + l4;
#pragma unroll
  for (int mt = 0; mt < 4; ++mt)
#pragma unroll
    for (int nt = 0; nt < 4; ++nt) {
      int j = jb + nt * 16;
#pragma unroll
      for (int r = 0; r < 4; ++r) {
        int i = ib + mt * 16 + r;
        float s = acc[mt][nt][r] * SC;
        if (j == (i ^ 4096)) { pos[i] = s; pos[j] = s; }
        float e = (i == j) ? 0.f : __expf(s);
        rs[mt][r] += e;
        if (!diag) cs[nt] += e;
      }
    }
#pragma unroll
  for (int mt = 0; mt < 4; ++mt)
#pragma unroll
    for (int r = 0; r < 4; ++r) {
      float v = rs[mt][r];
      v += __shfl_xor(v, 1); v += __shfl_xor(v, 2);
      v += __shfl_xor(v, 4); v += __shfl_xor(v, 8);
      rs[mt][r] = v;
    }
  int sel = l4;
  float myv = rs[0][0];
#pragma unroll
  for (int mt = 0; mt < 4; ++mt)
#pragma unroll
    for (int r = 0; r < 4; ++r)
      if (sel == mt * 4 + r) myv = rs[mt][r];
  int rowi = i0 + wm * 64 + (sel >> 2) * 16 + ((L >> 4) << 2) + (sel & 3);
  atomicAdd(&sumexp[rowi], myv);
  if (!diag) {
#pragma unroll
    for (int nt = 0; nt < 4; ++nt) {
      float v = cs[nt];
      v += __shfl_xor(v, 16); v += __shfl_xor(v, 32);
      if ((L >> 4) == 0) atomicAdd(&sumexp[jb + nt * 16], v);
    }
  }
}

// -------- finalize: out += mean-partial(log(sumexp) - pos), 16 blocks --------
__global__ __launch_bounds__(512) void finalize_kernel(
    const float* __restrict__ sumexp, const float* __restrict__ pos,
    float* __restrict__ out) {
  int t = threadIdx.x;
  int i = blockIdx.x * 512 + t;
  float s = logf(sumexp[i]) - pos[i];
#pragma unroll
  for (int off = 1; off < 64; off <<= 1) s += __shfl_xor(s, off);
  __shared__ float red[8];
  if ((t & 63) == 0) red[t >> 6] = s;
  __syncthreads();
  if (t == 0) {
    float tot = 0.f;
    for (int k2 = 0; k2 < 8; ++k2) tot += red[k2];
    atomicAdd(out, tot * (1.0f / 8192.0f));
  }
}

extern "C" void kernel_launch(void* const* d_in, const int* in_sizes, int n_in,
                              void* d_out, int out_size, void* d_ws, size_t ws_size,
                              hipStream_t stream) {
  const float* x = (const float*)d_in[0];
  const float* w = (const float*)d_in[1];
  const float* b = (const float*)d_in[2];
  float* out = (float*)d_out;
  char* ws = (char*)d_ws;
  unsigned char* wt8 = (unsigned char*)(ws);
  unsigned char* x8  = (unsigned char*)(ws + 1048576);
  unsigned short* z  = (unsigned short*)(ws + 17825792);
  unsigned char* zn8 = (unsigned char*)(ws + 68157440);
  float* sumexp      = (float*)(ws + 84934656);
  float* pos         = (float*)(ws + 84967424);

  prep2_kernel<<<16384, 256, 0, stream>>>(x, w, x8, wt8, sumexp, out);
  gemm1q_kernel<<<512, 256, 0, stream>>>(x8, wt8, b, z);
  norm_kernel<<<8192, 256, 0, stream>>>(z, zn8);
  gemm2_kernel<<<2080, 256, 0, stream>>>(zn8, sumexp, pos);
  finalize_kernel<<<16, 512, 0, stream>>>(sumexp, pos, out);
}